// Round 2
// baseline (1127.517 us; speedup 1.0000x reference)
//
#include <hip/hip_runtime.h>
#include <hip/hip_cooperative_groups.h>

typedef unsigned long long u64;
#define V0TOK 32000
#define EDIM  1024

__device__ __forceinline__ float dot4(float4 a, float4 b) {
    return fmaf(a.x, b.x, fmaf(a.y, b.y, fmaf(a.z, b.z, a.w * b.w)));
}

// ---------------------------------------------------------------------------
// Cooperative RNN kernel: 256 blocks x 256 threads (1 block/CU).
// Block b owns h-indices j = 4b+w (wave w). Wave w owns GRU rows
// {j, 1024+j, 2048+j}. W_ih/W_hh rows live in VGPRs (lane l holds float4
// slices at index l+64m). h is exchanged via {tag,value} packed u64 agent
// atomics (dataflow; no per-step grid sync). Rank-1 dependence of h gives
// natural distance-2 backpressure, so 2 slots suffice.
// ---------------------------------------------------------------------------
__global__ __launch_bounds__(256, 1) void k_rnn(
    const int* __restrict__ diag, const int* __restrict__ proc,
    const int* __restrict__ med,  const int* __restrict__ dtok,
    const float* __restrict__ enc, const float* __restrict__ dec,
    const float* __restrict__ attw,
    const float* __restrict__ wih, const float* __restrict__ whh,
    const float* __restrict__ bih, const float* __restrict__ bhh,
    float* __restrict__ ctx_ws, float* __restrict__ c_ws,
    u64* __restrict__ htag, float* __restrict__ hrelu)
{
    const int b = blockIdx.x, tid = threadIdx.x;
    const int w = tid >> 6, l = tid & 63;

    __shared__ float sm[320];
    __shared__ float red1[4], red2[4];
    __shared__ float hlds[1024];

    // ---- Phase A: clear tags (replay determinism) + ctx scores ----
    if (tid < 4) {
        __hip_atomic_store(&htag[4*b + tid],        0ull, __ATOMIC_RELAXED, __HIP_MEMORY_SCOPE_AGENT);
        __hip_atomic_store(&htag[1024 + 4*b + tid], 0ull, __ATOMIC_RELAXED, __HIP_MEMORY_SCOPE_AGENT);
    }
    if (b < 80) {
        int i = 4*b + w;   // 0..319
        int ridx = (i < 128) ? diag[i] : (i < 192 ? proc[i-128] : med[i-192]);
        const float4* row = (const float4*)(enc + (size_t)ridx * EDIM);
        const float4* we  = (const float4*)(attw + EDIM);   // w_e = attn_w[0, E:]
        float p = 0.f;
        #pragma unroll
        for (int m = 0; m < 4; m++) p += dot4(row[l + 64*m], we[l + 64*m]);
        #pragma unroll
        for (int off = 32; off; off >>= 1) p += __shfl_xor(p, off);
        if (l == 0) ctx_ws[i] = p;
    }
    __threadfence();
    cooperative_groups::this_grid().sync();
    __threadfence();

    // ---- Phase B: per-block softmax (redundant, avoids a sync) + c slice ----
    {
        float s1 = ctx_ws[tid];
        float s2 = (tid < 64) ? ctx_ws[256 + tid] : -1e30f;
        float mx = fmaxf(s1, s2);
        #pragma unroll
        for (int off = 32; off; off >>= 1) mx = fmaxf(mx, __shfl_xor(mx, off));
        if (l == 0) red1[w] = mx;
        __syncthreads();
        mx = fmaxf(fmaxf(red1[0], red1[1]), fmaxf(red1[2], red1[3]));
        float e1 = expf(s1 - mx);
        float e2 = (tid < 64) ? expf(s2 - mx) : 0.f;
        float ss = e1 + e2;
        #pragma unroll
        for (int off = 32; off; off >>= 1) ss += __shfl_xor(ss, off);
        if (l == 0) red2[w] = ss;
        __syncthreads();
        float tot = red2[0] + red2[1] + red2[2] + red2[3];
        sm[tid] = e1 / tot;
        if (tid < 64) sm[256 + tid] = e2 / tot;
        __syncthreads();

        int e = 4*b + w;   // c element this wave produces
        float p = 0.f;
        for (int i = l; i < 320; i += 64) {
            int ridx = (i < 128) ? diag[i] : (i < 192 ? proc[i-128] : med[i-192]);
            p += sm[i] * enc[(size_t)ridx * EDIM + e];
        }
        #pragma unroll
        for (int off = 32; off; off >>= 1) p += __shfl_xor(p, off);
        if (l == 0) c_ws[e] = p;
    }
    __threadfence();
    cooperative_groups::this_grid().sync();
    __threadfence();

    // ---- Phase C: weights -> VGPRs, constants, then the recurrence ----
    const int jr = 4*b + w, jz = 1024 + jr, jn = 2048 + jr;

    float4 wir[8], wiz[8], win[8];
    float4 whr[4], whz[4], whn[4];
    {
        const float4* pr = (const float4*)(wih + (size_t)jr * 2048);
        const float4* pz = (const float4*)(wih + (size_t)jz * 2048);
        const float4* pn = (const float4*)(wih + (size_t)jn * 2048);
        #pragma unroll
        for (int m = 0; m < 8; m++) { wir[m] = pr[l + 64*m]; wiz[m] = pz[l + 64*m]; win[m] = pn[l + 64*m]; }
        const float4* qr = (const float4*)(whh + (size_t)jr * 1024);
        const float4* qz = (const float4*)(whh + (size_t)jz * 1024);
        const float4* qn = (const float4*)(whh + (size_t)jn * 1024);
        #pragma unroll
        for (int m = 0; m < 4; m++) { whr[m] = qr[l + 64*m]; whz[m] = qz[l + 64*m]; whn[m] = qn[l + 64*m]; }
    }
    float4 c4[4], h4[4];
    {
        const float4* cp = (const float4*)c_ws;
        const float4* hp = (const float4*)(dec + (size_t)V0TOK * EDIM);  // h0 = dec_x[0]
        #pragma unroll
        for (int m = 0; m < 4; m++) { c4[m] = cp[l + 64*m]; h4[m] = hp[l + 64*m]; }
    }
    const float b_r  = bih[jr] + bhh[jr];
    const float b_z  = bih[jz] + bhh[jz];
    const float b_ni = bih[jn];
    const float b_nh = bhh[jn];

    // constant c-half of gi (lane partials)
    float gic_r = 0.f, gic_z = 0.f, gic_n = 0.f;
    #pragma unroll
    for (int m = 0; m < 4; m++) {
        gic_r += dot4(wir[m], c4[m]); gic_z += dot4(wiz[m], c4[m]); gic_n += dot4(win[m], c4[m]);
    }

    for (int t = 0; t < 65; t++) {
        const int tok = (t == 0) ? V0TOK : dtok[t - 1];
        const float4* xp = (const float4*)(dec + (size_t)tok * EDIM);

        float gr = gic_r, gz = gic_z, gn = gic_n;
        #pragma unroll
        for (int m = 0; m < 4; m++) {
            float4 x = xp[l + 64*m];
            gr += dot4(wir[4+m], x); gz += dot4(wiz[4+m], x); gn += dot4(win[4+m], x);
        }
        float hr = 0.f, hz = 0.f, hn = 0.f;
        #pragma unroll
        for (int m = 0; m < 4; m++) {
            hr += dot4(whr[m], h4[m]); hz += dot4(whz[m], h4[m]); hn += dot4(whn[m], h4[m]);
        }
        float sr = gr + hr, sz = gz + hz, sni = gn, snh = hn;
        #pragma unroll
        for (int off = 32; off; off >>= 1) {
            sr  += __shfl_xor(sr, off);  sz  += __shfl_xor(sz, off);
            sni += __shfl_xor(sni, off); snh += __shfl_xor(snh, off);
        }
        float rg = 1.f / (1.f + expf(-(sr + b_r)));
        float zg = 1.f / (1.f + expf(-(sz + b_z)));
        float ng = tanhf(sni + b_ni + rg * (snh + b_nh));

        // h_t[j]: j = 4b+w -> float4 h4[b>>6], component w, lane b&63
        int mi = b >> 6;
        float4 hs = (mi == 0) ? h4[0] : (mi == 1) ? h4[1] : (mi == 2) ? h4[2] : h4[3];
        float hv = (w == 0) ? hs.x : (w == 1) ? hs.y : (w == 2) ? hs.z : hs.w;
        hv = __shfl(hv, b & 63);
        float hnew = (1.f - zg) * ng + zg * hv;

        if (l == 0) {
            hrelu[t * 1024 + jr] = fmaxf(hnew, 0.f);
            u64 pk = ((u64)(unsigned)(t + 1) << 32) | (u64)__float_as_uint(hnew);
            __hip_atomic_store(&htag[((t + 1) & 1) * 1024 + jr], pk,
                               __ATOMIC_RELAXED, __HIP_MEMORY_SCOPE_AGENT);
        }

        if (t < 64) {
            if (w == 0) {  // wave 0 gathers h_{t+1}, shares via LDS
                u64* slot = htag + ((t + 1) & 1) * 1024;
                const unsigned want = (unsigned)(t + 1);
                u64 v[16];
                while (1) {
                    #pragma unroll
                    for (int m = 0; m < 4; m++)
                        #pragma unroll
                        for (int c = 0; c < 4; c++)
                            v[4*m + c] = __hip_atomic_load(&slot[4*l + 256*m + c],
                                                           __ATOMIC_RELAXED, __HIP_MEMORY_SCOPE_AGENT);
                    bool ok = true;
                    #pragma unroll
                    for (int q = 0; q < 16; q++) ok &= ((unsigned)(v[q] >> 32) == want);
                    if (__all(ok)) break;
                }
                #pragma unroll
                for (int m = 0; m < 4; m++) {
                    float4 nh;
                    nh.x = __uint_as_float((unsigned)v[4*m + 0]);
                    nh.y = __uint_as_float((unsigned)v[4*m + 1]);
                    nh.z = __uint_as_float((unsigned)v[4*m + 2]);
                    nh.w = __uint_as_float((unsigned)v[4*m + 3]);
                    h4[m] = nh;
                    ((float4*)hlds)[l + 64*m] = nh;
                }
            }
            __syncthreads();
            if (w != 0) {
                #pragma unroll
                for (int m = 0; m < 4; m++) h4[m] = ((const float4*)hlds)[l + 64*m];
            }
            __syncthreads();  // keep wave0's next hlds write behind these reads
        }
    }
}

// ---------------------------------------------------------------------------
// logits = out_w @ relu(H)^T + out_b.  Block: 32 v-rows x all 65 t.
// Waves 0-3: lane=t (0..63), 8 v-rows each, W via wave-uniform (scalar) loads.
// Wave 4: t=64 matvec for the block's 32 rows, lane=k; needs cross-lane
// reduction at the end (bias added on lane 0 only).
// ---------------------------------------------------------------------------
__global__ __launch_bounds__(320) void k_logits(
    const float* __restrict__ wo, const float* __restrict__ bo,
    const float* __restrict__ hrelu, float* __restrict__ out)
{
    __shared__ float Hs[65 * 68];   // row stride 68 floats: 16B-aligned, conflict-free
    const int tid = threadIdx.x, w = tid >> 6, l = tid & 63;
    const int v0 = blockIdx.x * 32;

    float acc[8];
    float acc4[32];
    const float* wrow[8];

    if (w < 4) {
        #pragma unroll
        for (int i = 0; i < 8; i++) {
            int v = v0 + 8*w + i;
            acc[i] = (v < 32002) ? bo[v] : 0.f;
            wrow[i] = wo + (size_t)((v < 32002) ? v : 0) * 1024;
        }
    } else {
        #pragma unroll
        for (int i = 0; i < 32; i++) acc4[i] = 0.f;   // per-lane k-partials; bias after reduce
    }

    for (int kk = 0; kk < 1024; kk += 64) {
        __syncthreads();
        for (int idx = tid; idx < 65 * 64; idx += 320) {   // 13 exact iters
            int t = idx >> 6, k = idx & 63;
            Hs[t * 68 + k] = hrelu[t * 1024 + kk + k];
        }
        __syncthreads();

        if (w < 4) {
            const float* hrow = Hs + l * 68;   // lane l == t
            #pragma unroll
            for (int q = 0; q < 16; q++) {
                float4 h4 = *(const float4*)(hrow + 4*q);
                #pragma unroll
                for (int i = 0; i < 8; i++) {
                    float4 wv = *(const float4*)(wrow[i] + kk + 4*q);  // wave-uniform
                    acc[i] = fmaf(h4.x, wv.x, acc[i]);
                    acc[i] = fmaf(h4.y, wv.y, acc[i]);
                    acc[i] = fmaf(h4.z, wv.z, acc[i]);
                    acc[i] = fmaf(h4.w, wv.w, acc[i]);
                }
            }
        } else {
            float h64v = Hs[64 * 68 + l];
            #pragma unroll
            for (int i = 0; i < 32; i++) {
                int v = v0 + i;
                const float* wp = wo + (size_t)((v < 32002) ? v : 0) * 1024 + kk + l;
                acc4[i] = fmaf(*wp, h64v, acc4[i]);
            }
        }
    }

    if (w < 4) {
        #pragma unroll
        for (int i = 0; i < 8; i++) {
            int v = v0 + 8*w + i;
            if (v < 32002) out[(size_t)l * 32002 + v] = acc[i];
        }
    } else {
        // cross-lane reduction: acc4[i] holds this lane's k-partial of row v0+i
        #pragma unroll
        for (int i = 0; i < 32; i++) {
            float s = acc4[i];
            #pragma unroll
            for (int off = 32; off; off >>= 1) s += __shfl_xor(s, off);
            int v = v0 + i;
            if (l == 0 && v < 32002) out[(size_t)64 * 32002 + v] = s + bo[v];
        }
    }
}

// ---------------------------------------------------------------------------
extern "C" void kernel_launch(void* const* d_in, const int* in_sizes, int n_in,
                              void* d_out, int out_size, void* d_ws, size_t ws_size,
                              hipStream_t stream) {
    const int*   diag = (const int*)d_in[0];
    const int*   proc = (const int*)d_in[1];
    const int*   med  = (const int*)d_in[2];
    const int*   dtok = (const int*)d_in[3];
    const float* enc  = (const float*)d_in[4];
    const float* dec  = (const float*)d_in[5];
    const float* attw = (const float*)d_in[6];
    // d_in[7] = attn_b: uniform shift, cancels in softmax -> unused
    const float* wih  = (const float*)d_in[8];
    const float* whh  = (const float*)d_in[9];
    const float* bih  = (const float*)d_in[10];
    const float* bhh  = (const float*)d_in[11];
    const float* wo   = (const float*)d_in[12];
    const float* bo   = (const float*)d_in[13];
    float* out = (float*)d_out;

    // ws layout: [0,1280) ctx_score | [2048,6144) c | [8192,24576) htag | [32768,+266240) Hrelu
    float* ctx_ws = (float*)d_ws;
    float* c_ws   = (float*)((char*)d_ws + 2048);
    u64*   htag   = (u64*)  ((char*)d_ws + 8192);
    float* hrelu  = (float*)((char*)d_ws + 32768);

    void* args[] = { (void*)&diag, (void*)&proc, (void*)&med, (void*)&dtok,
                     (void*)&enc, (void*)&dec, (void*)&attw,
                     (void*)&wih, (void*)&whh, (void*)&bih, (void*)&bhh,
                     (void*)&ctx_ws, (void*)&c_ws, (void*)&htag, (void*)&hrelu };
    hipLaunchCooperativeKernel((void*)k_rnn, dim3(256), dim3(256), args, 0, stream);

    k_logits<<<dim3(1001), dim3(320), 0, stream>>>(wo, bo, hrelu, out);
}

// Round 3
// 1010.170 us; speedup vs baseline: 1.1162x; 1.1162x over previous
//
#include <hip/hip_runtime.h>
#include <hip/hip_cooperative_groups.h>

typedef unsigned long long u64;
#define V0TOK 32000
#define EDIM  1024

__device__ __forceinline__ float dot4(float4 a, float4 b) {
    return fmaf(a.x, b.x, fmaf(a.y, b.y, fmaf(a.z, b.z, a.w * b.w)));
}

// ---------------------------------------------------------------------------
// Cooperative RNN kernel: 256 blocks x 256 threads (1 block/CU).
// Block b owns h-indices j = 4b+w (wave w): GRU rows {j, 1024+j, 2048+j}.
// W_hh rows (critical path) in VGPRs (12 float4/lane). W_ih x-half rows in
// LDS (48KB). W_ih c-half folded into per-step constants gic_* (streamed
// once). h exchanged via {tag,value} packed u64 agent atomics; all 4 waves
// poll a quarter each. gx(t+1) computed between h-store and poll to hide
// store-visibility latency.
// ---------------------------------------------------------------------------
__global__ __launch_bounds__(256, 1) void k_rnn(
    const int* __restrict__ diag, const int* __restrict__ proc,
    const int* __restrict__ med,  const int* __restrict__ dtok,
    const float* __restrict__ enc, const float* __restrict__ dec,
    const float* __restrict__ attw,
    const float* __restrict__ wih, const float* __restrict__ whh,
    const float* __restrict__ bih, const float* __restrict__ bhh,
    float* __restrict__ ctx_ws, float* __restrict__ c_ws,
    u64* __restrict__ htag, float* __restrict__ hrelu)
{
    const int b = blockIdx.x, tid = threadIdx.x;
    const int w = tid >> 6, l = tid & 63;

    __shared__ float Wx[12 * 1024];     // 48KB: W_ih x-half rows, row index g*4+w
    __shared__ float sm[320];
    __shared__ float red1[4], red2[4];
    __shared__ float hlds[1024];

    // ---- Phase A: clear tags (replay determinism) + ctx scores ----
    if (tid < 4) {
        __hip_atomic_store(&htag[4*b + tid],        0ull, __ATOMIC_RELAXED, __HIP_MEMORY_SCOPE_AGENT);
        __hip_atomic_store(&htag[1024 + 4*b + tid], 0ull, __ATOMIC_RELAXED, __HIP_MEMORY_SCOPE_AGENT);
    }
    if (b < 80) {
        int i = 4*b + w;   // 0..319
        int ridx = (i < 128) ? diag[i] : (i < 192 ? proc[i-128] : med[i-192]);
        const float4* row = (const float4*)(enc + (size_t)ridx * EDIM);
        const float4* we  = (const float4*)(attw + EDIM);   // w_e = attn_w[0, E:]
        float p = 0.f;
        #pragma unroll
        for (int m = 0; m < 4; m++) p += dot4(row[l + 64*m], we[l + 64*m]);
        #pragma unroll
        for (int off = 32; off; off >>= 1) p += __shfl_xor(p, off);
        if (l == 0) ctx_ws[i] = p;
    }
    __threadfence();
    cooperative_groups::this_grid().sync();
    __threadfence();

    // ---- Phase B: per-block softmax (redundant, avoids a sync) + c slice ----
    {
        float s1 = ctx_ws[tid];
        float s2 = (tid < 64) ? ctx_ws[256 + tid] : -1e30f;
        float mx = fmaxf(s1, s2);
        #pragma unroll
        for (int off = 32; off; off >>= 1) mx = fmaxf(mx, __shfl_xor(mx, off));
        if (l == 0) red1[w] = mx;
        __syncthreads();
        mx = fmaxf(fmaxf(red1[0], red1[1]), fmaxf(red1[2], red1[3]));
        float e1 = expf(s1 - mx);
        float e2 = (tid < 64) ? expf(s2 - mx) : 0.f;
        float ss = e1 + e2;
        #pragma unroll
        for (int off = 32; off; off >>= 1) ss += __shfl_xor(ss, off);
        if (l == 0) red2[w] = ss;
        __syncthreads();
        float tot = red2[0] + red2[1] + red2[2] + red2[3];
        sm[tid] = e1 / tot;
        if (tid < 64) sm[256 + tid] = e2 / tot;
        __syncthreads();

        int e = 4*b + w;   // c element this wave produces
        float p = 0.f;
        for (int i = l; i < 320; i += 64) {
            int ridx = (i < 128) ? diag[i] : (i < 192 ? proc[i-128] : med[i-192]);
            p += sm[i] * enc[(size_t)ridx * EDIM + e];
        }
        #pragma unroll
        for (int off = 32; off; off >>= 1) p += __shfl_xor(p, off);
        if (l == 0) c_ws[e] = p;
    }
    __threadfence();
    cooperative_groups::this_grid().sync();
    __threadfence();

    // ---- Phase C ----
    const int jr = 4*b + w, jz = 1024 + jr, jn = 2048 + jr;

    // Stage W_ih x-half rows into LDS (each wave writes & later reads its own 3 rows)
    {
        const float4* s_r = (const float4*)(wih + (size_t)jr * 2048 + 1024);
        const float4* s_z = (const float4*)(wih + (size_t)jz * 2048 + 1024);
        const float4* s_n = (const float4*)(wih + (size_t)jn * 2048 + 1024);
        float4* d_r = (float4*)(Wx + (0*4 + w) * 1024);
        float4* d_z = (float4*)(Wx + (1*4 + w) * 1024);
        float4* d_n = (float4*)(Wx + (2*4 + w) * 1024);
        #pragma unroll
        for (int m = 0; m < 4; m++) {
            d_r[l + 64*m] = s_r[l + 64*m];
            d_z[l + 64*m] = s_z[l + 64*m];
            d_n[l + 64*m] = s_n[l + 64*m];
        }
    }

    // W_hh rows -> VGPRs (only 48 regs/lane)
    float4 whr[4], whz[4], whn[4];
    {
        const float4* qr = (const float4*)(whh + (size_t)jr * 1024);
        const float4* qz = (const float4*)(whh + (size_t)jz * 1024);
        const float4* qn = (const float4*)(whh + (size_t)jn * 1024);
        #pragma unroll
        for (int m = 0; m < 4; m++) { whr[m] = qr[l + 64*m]; whz[m] = qz[l + 64*m]; whn[m] = qn[l + 64*m]; }
    }

    float4 c4[4], h4[4];
    {
        const float4* cp = (const float4*)c_ws;
        const float4* hp = (const float4*)(dec + (size_t)V0TOK * EDIM);  // h0 = dec_x[0] = x_0
        #pragma unroll
        for (int m = 0; m < 4; m++) { c4[m] = cp[l + 64*m]; h4[m] = hp[l + 64*m]; }
    }
    const float b_r  = bih[jr] + bhh[jr];
    const float b_z  = bih[jz] + bhh[jz];
    const float b_ni = bih[jn];
    const float b_nh = bhh[jn];

    // gic = W_ih(c-half) @ c  (streamed once from global, lane partials)
    float gic_r = 0.f, gic_z = 0.f, gic_n = 0.f;
    {
        const float4* pr = (const float4*)(wih + (size_t)jr * 2048);
        const float4* pz = (const float4*)(wih + (size_t)jz * 2048);
        const float4* pn = (const float4*)(wih + (size_t)jn * 2048);
        #pragma unroll
        for (int m = 0; m < 4; m++) {
            gic_r += dot4(pr[l + 64*m], c4[m]);
            gic_z += dot4(pz[l + 64*m], c4[m]);
            gic_n += dot4(pn[l + 64*m], c4[m]);
        }
    }

    __syncthreads();   // Wx staged

    const float4* WxR = (const float4*)(Wx + (0*4 + w) * 1024);
    const float4* WxZ = (const float4*)(Wx + (1*4 + w) * 1024);
    const float4* WxN = (const float4*)(Wx + (2*4 + w) * 1024);

    // token preload: lane l holds dtok[l]
    int tokreg = dtok[l];

    // gx for t=0 (x_0 == h0 row, already in h4)
    float gxr = gic_r, gxz = gic_z, gxn = gic_n;
    #pragma unroll
    for (int m = 0; m < 4; m++) {
        gxr += dot4(WxR[l + 64*m], h4[m]);
        gxz += dot4(WxZ[l + 64*m], h4[m]);
        gxn += dot4(WxN[l + 64*m], h4[m]);
    }
    // prefetch x_1
    float4 xv[4];
    {
        int tok1 = __shfl(tokreg, 0);
        const float4* xp = (const float4*)(dec + (size_t)tok1 * EDIM);
        #pragma unroll
        for (int m = 0; m < 4; m++) xv[m] = xp[l + 64*m];
    }

    for (int t = 0; t < 65; t++) {
        // h-part: pure VGPR FMAs
        float hr = 0.f, hz = 0.f, hn_ = 0.f;
        #pragma unroll
        for (int m = 0; m < 4; m++) {
            hr  += dot4(whr[m], h4[m]);
            hz  += dot4(whz[m], h4[m]);
            hn_ += dot4(whn[m], h4[m]);
        }
        float sr = gxr + hr, sz = gxz + hz, sni = gxn, snh = hn_;
        #pragma unroll
        for (int off = 32; off; off >>= 1) {
            sr  += __shfl_xor(sr, off);  sz  += __shfl_xor(sz, off);
            sni += __shfl_xor(sni, off); snh += __shfl_xor(snh, off);
        }
        float rg = 1.f / (1.f + expf(-(sr + b_r)));
        float zg = 1.f / (1.f + expf(-(sz + b_z)));
        float ng = tanhf(sni + b_ni + rg * (snh + b_nh));

        // h_t[j]: j = 4b+w -> h4[b>>6], component w, lane b&63
        int mi = b >> 6;
        float4 hs = (mi == 0) ? h4[0] : (mi == 1) ? h4[1] : (mi == 2) ? h4[2] : h4[3];
        float hv = (w == 0) ? hs.x : (w == 1) ? hs.y : (w == 2) ? hs.z : hs.w;
        hv = __shfl(hv, b & 63);
        float hnew = (1.f - zg) * ng + zg * hv;

        if (l == 0) {
            hrelu[t * 1024 + jr] = fmaxf(hnew, 0.f);
            u64 pk = ((u64)(unsigned)(t + 1) << 32) | (u64)__float_as_uint(hnew);
            __hip_atomic_store(&htag[((t + 1) & 1) * 1024 + jr], pk,
                               __ATOMIC_RELAXED, __HIP_MEMORY_SCOPE_AGENT);
        }

        if (t < 64) {
            // ---- overlap window: compute gx(t+1) while stores become visible ----
            gxr = gic_r; gxz = gic_z; gxn = gic_n;
            #pragma unroll
            for (int m = 0; m < 4; m++) {
                gxr += dot4(WxR[l + 64*m], xv[m]);
                gxz += dot4(WxZ[l + 64*m], xv[m]);
                gxn += dot4(WxN[l + 64*m], xv[m]);
            }
            if (t < 63) {   // prefetch x_{t+2}
                int tok = __shfl(tokreg, t + 1);
                const float4* xp = (const float4*)(dec + (size_t)tok * EDIM);
                #pragma unroll
                for (int m = 0; m < 4; m++) xv[m] = xp[l + 64*m];
            }

            // ---- poll: wave w gathers h quarter [256w, 256w+256) ----
            {
                u64* slot = htag + ((t + 1) & 1) * 1024 + 256 * w;
                const unsigned want = (unsigned)(t + 1);
                u64 v[4];
                while (1) {
                    #pragma unroll
                    for (int c = 0; c < 4; c++)
                        v[c] = __hip_atomic_load(&slot[4*l + c],
                                                 __ATOMIC_RELAXED, __HIP_MEMORY_SCOPE_AGENT);
                    bool ok = true;
                    #pragma unroll
                    for (int q = 0; q < 4; q++) ok &= ((unsigned)(v[q] >> 32) == want);
                    if (__all(ok)) break;
                }
                float4 nh;
                nh.x = __uint_as_float((unsigned)v[0]);
                nh.y = __uint_as_float((unsigned)v[1]);
                nh.z = __uint_as_float((unsigned)v[2]);
                nh.w = __uint_as_float((unsigned)v[3]);
                ((float4*)hlds)[64*w + l] = nh;
            }
            __syncthreads();
            #pragma unroll
            for (int m = 0; m < 4; m++) h4[m] = ((const float4*)hlds)[l + 64*m];
            __syncthreads();   // keep next iteration's hlds writes behind these reads
        }
    }
}

// ---------------------------------------------------------------------------
// logits = out_w @ relu(H)^T + out_b.  Block: 32 v-rows x all 65 t.
// Waves 0-3: lane=t (0..63), 8 v-rows each; W addressing made provably
// wave-uniform via readfirstlane -> scalar loads; loads batched ahead of FMAs.
// Wave 4: t=64 matvec, lane=k, butterfly-reduced. Output staged in LDS and
// stored coalesced.
// ---------------------------------------------------------------------------
__global__ __launch_bounds__(320) void k_logits(
    const float* __restrict__ wo, const float* __restrict__ bo,
    const float* __restrict__ hrelu, float* __restrict__ out)
{
    __shared__ float Hs[65 * 68];   // staging; reused as Os (stride 33) at the end
    const int tid = threadIdx.x;
    const int w = __builtin_amdgcn_readfirstlane(tid >> 6);   // provably uniform
    const int l = tid & 63;
    const int v0 = blockIdx.x * 32;

    float acc[8];
    float acc4[32];
    const float* wrow[8];

    if (w < 4) {
        #pragma unroll
        for (int i = 0; i < 8; i++) {
            int v = v0 + 8*w + i;
            acc[i] = (v < 32002) ? bo[v] : 0.f;
            wrow[i] = wo + (size_t)((v < 32002) ? v : 0) * 1024;
        }
    } else {
        #pragma unroll
        for (int i = 0; i < 32; i++) acc4[i] = 0.f;
    }

    for (int kk = 0; kk < 1024; kk += 64) {
        __syncthreads();
        for (int idx = tid; idx < 65 * 16; idx += 320) {     // float4 staging
            int t = idx >> 4, k4 = idx & 15;
            *(float4*)(Hs + t * 68 + 4 * k4) =
                *(const float4*)(hrelu + t * 1024 + kk + 4 * k4);
        }
        __syncthreads();

        if (w < 4) {
            const float* hrow = Hs + l * 68;   // lane l == t
            #pragma unroll
            for (int q = 0; q < 16; q += 2) {
                float4 h0 = *(const float4*)(hrow + 4*q);
                float4 h1 = *(const float4*)(hrow + 4*q + 4);
                float4 wv0[8], wv1[8];
                #pragma unroll
                for (int i = 0; i < 8; i++) wv0[i] = *(const float4*)(wrow[i] + kk + 4*q);
                #pragma unroll
                for (int i = 0; i < 8; i++) wv1[i] = *(const float4*)(wrow[i] + kk + 4*q + 4);
                #pragma unroll
                for (int i = 0; i < 8; i++) {
                    acc[i] = fmaf(h0.x, wv0[i].x, acc[i]);
                    acc[i] = fmaf(h0.y, wv0[i].y, acc[i]);
                    acc[i] = fmaf(h0.z, wv0[i].z, acc[i]);
                    acc[i] = fmaf(h0.w, wv0[i].w, acc[i]);
                    acc[i] = fmaf(h1.x, wv1[i].x, acc[i]);
                    acc[i] = fmaf(h1.y, wv1[i].y, acc[i]);
                    acc[i] = fmaf(h1.z, wv1[i].z, acc[i]);
                    acc[i] = fmaf(h1.w, wv1[i].w, acc[i]);
                }
            }
        } else {
            float h64v = Hs[64 * 68 + l];
            #pragma unroll
            for (int i = 0; i < 32; i++) {
                int v = v0 + i;
                const float* wp = wo + (size_t)((v < 32002) ? v : 0) * 1024 + kk + l;
                acc4[i] = fmaf(*wp, h64v, acc4[i]);
            }
        }
    }

    __syncthreads();                  // Hs reads done; reuse as Os
    float* Os = Hs;                   // [64 t][stride 33]
    if (w < 4) {
        #pragma unroll
        for (int i = 0; i < 8; i++) Os[l * 33 + 8*w + i] = acc[i];
    } else {
        // t=64 row: butterfly-reduce k-partials, lane 0 writes
        #pragma unroll
        for (int i = 0; i < 32; i++) {
            float s = acc4[i];
            #pragma unroll
            for (int off = 32; off; off >>= 1) s += __shfl_xor(s, off);
            int v = v0 + i;
            if (l == 0 && v < 32002) out[(size_t)64 * 32002 + v] = s + bo[v];
        }
    }
    __syncthreads();
    for (int idx = tid; idx < 64 * 32; idx += 320) {   // coalesced t<64 stores
        int t = idx >> 5, c = idx & 31;
        int v = v0 + c;
        if (v < 32002) out[(size_t)t * 32002 + v] = Os[t * 33 + c];
    }
}

// ---------------------------------------------------------------------------
extern "C" void kernel_launch(void* const* d_in, const int* in_sizes, int n_in,
                              void* d_out, int out_size, void* d_ws, size_t ws_size,
                              hipStream_t stream) {
    const int*   diag = (const int*)d_in[0];
    const int*   proc = (const int*)d_in[1];
    const int*   med  = (const int*)d_in[2];
    const int*   dtok = (const int*)d_in[3];
    const float* enc  = (const float*)d_in[4];
    const float* dec  = (const float*)d_in[5];
    const float* attw = (const float*)d_in[6];
    // d_in[7] = attn_b: uniform shift, cancels in softmax -> unused
    const float* wih  = (const float*)d_in[8];
    const float* whh  = (const float*)d_in[9];
    const float* bih  = (const float*)d_in[10];
    const float* bhh  = (const float*)d_in[11];
    const float* wo   = (const float*)d_in[12];
    const float* bo   = (const float*)d_in[13];
    float* out = (float*)d_out;

    // ws layout: [0,1280) ctx_score | [2048,6144) c | [8192,24576) htag | [32768,+266240) Hrelu
    float* ctx_ws = (float*)d_ws;
    float* c_ws   = (float*)((char*)d_ws + 2048);
    u64*   htag   = (u64*)  ((char*)d_ws + 8192);
    float* hrelu  = (float*)((char*)d_ws + 32768);

    void* args[] = { (void*)&diag, (void*)&proc, (void*)&med, (void*)&dtok,
                     (void*)&enc, (void*)&dec, (void*)&attw,
                     (void*)&wih, (void*)&whh, (void*)&bih, (void*)&bhh,
                     (void*)&ctx_ws, (void*)&c_ws, (void*)&htag, (void*)&hrelu };
    hipLaunchCooperativeKernel((void*)k_rnn, dim3(256), dim3(256), args, 0, stream);

    k_logits<<<dim3(1001), dim3(320), 0, stream>>>(wo, bo, hrelu, out);
}